// Round 3
// baseline (216.484 us; speedup 1.0000x reference)
//
#include <hip/hip_runtime.h>
#include <hip/hip_bf16.h>

// ---- problem constants -----------------------------------------------------
#define ZZ      87
#define NREF    7
#define NC      5
#define NW      23
#define NATOMS  75000
#define NPAIRS  1500000

// derived
#define IAW     (ZZ*NREF*NW)        // 14007 alpha elements
#define RC6PAD  52                  // 49 (7x7) padded to 52 for float4 rows
#define NRC6    (ZZ*ZZ*RC6PAD)      // 393588

// ---- workspace layout (float offsets) --------------------------------------
// [0..4]  scalars: spq, s6, s8, a1, a2
#define OFF_CW      8               // 23: cpw * 3/(2pi)
#define OFF_ALPHA   32              // 14007
#define OFF_NCOORD  14080           // 75000   (memset each launch)
#define OFF_ENERGY  89080           // 75000   (memset each launch, contiguous)
#define OFF_ZETA    164080          // 75000*8 (row-padded, 16B aligned rows)
#define OFF_REFC6   764080          // 393588  (208B rows, 16B aligned)
// total = 1,157,668 floats = 4.63 MB

static constexpr float INV_BOHR  = (float)(1.0/0.5291772105638411);
static constexpr float HALF_HART = (float)(0.5*27.211386024367243);
static constexpr float CK4 = 4.10451f;
static constexpr float CK5 = 19.08857f;
static constexpr float INV_K6 = (float)(1.0/254.5553148552);
static constexpr float CKK = 7.5f;
static constexpr float E3F = 20.085536923187668f;       // e^3
static constexpr float C32PI = 0.47746482927568606f;    // 3/(2*pi)

// ---- dtype hedge: detect bf16 vs fp32 float tensors from s6_raw bits -------
// s6_raw = log(expm1(1)) = 0.5413248... ; fp32 bits 0x3F0A9444.
// first ushort: fp32 -> 0x9444 (hi byte 0x94), bf16 -> 0x3F0B (hi byte 0x3F).
__device__ __forceinline__ bool detect_bf16(const void* s6raw) {
    return ((*(const unsigned short*)s6raw) >> 8) == 0x3Fu;
}

__device__ __forceinline__ float ldf(const void* p, int i, bool bf) {
    if (bf) {
        unsigned int u = ((const unsigned short*)p)[i];
        return __uint_as_float(u << 16);
    }
    return ((const float*)p)[i];
}

__device__ __forceinline__ float splus(float x) {
    return (x > 15.f) ? x : log1pf(expf(x));
}

// ---- K1: scalars, scaled cpw, alpha table ----------------------------------
__global__ void k_prep(const int* __restrict__ refsys,
                       const void* zeff, const void* refh, const void* sscale,
                       const void* secaiw, const void* gam, const void* ascale,
                       const void* alphaiw, const void* hcount, const void* cpw,
                       const void* s6r, const void* s8r, const void* a1r,
                       const void* a2r, const void* sqr,
                       float* __restrict__ ws) {
    const bool bf = detect_bf16(s6r);
    int t = blockIdx.x * blockDim.x + threadIdx.x;
    if (t == 0) {
        ws[0] = splus(ldf(sqr, 0, bf));
        ws[1] = splus(ldf(s6r, 0, bf));
        ws[2] = splus(ldf(s8r, 0, bf));
        ws[3] = splus(ldf(a1r, 0, bf));
        ws[4] = splus(ldf(a2r, 0, bf));
    }
    if (t < NW) ws[OFF_CW + t] = C32PI * ldf(cpw, t, bf);
    if (t >= IAW) return;

    int w  = t % NW;
    int ia = t / NW;            // ia = i*NREF + a
    int rs = refsys[ia];

    float spq  = splus(ldf(sqr, 0, bf));
    float ze   = ldf(zeff, rs, bf);
    float qmod = ze + ldf(refh, ia, bf) * spq;
    float zfac;
    if (qmod > 1e-8f) {
        float g = ldf(gam, rs, bf);
        zfac = expf(3.f * (1.f - expf(2.f * g * (1.f - ze / qmod))));
    } else {
        zfac = E3F;
    }
    float sec = ldf(sscale, rs, bf) * ldf(secaiw, rs*NW + w, bf) * zfac;
    float al  = ldf(ascale, ia, bf) *
                (ldf(alphaiw, ia*NW + w, bf) - ldf(hcount, ia, bf) * sec);
    ws[OFF_ALPHA + t] = fmaxf(al, 0.f);
}

// ---- K2: refc6[i][j][a][b] (rows padded 49->52, pads zeroed) ----------------
__global__ void k_refc6(float* __restrict__ ws) {
    int t = blockIdx.x * blockDim.x + threadIdx.x;
    if (t >= NRC6) return;
    int e  = t % RC6PAD;
    int ij = t / RC6PAD;
    if (e >= 49) { ws[OFF_REFC6 + t] = 0.f; return; }
    int a = e / 7, b = e % 7;
    int i = ij / ZZ, j = ij % ZZ;
    const float* A  = ws + OFF_ALPHA;
    const float* CW = ws + OFF_CW;
    const float* Ai = A + (i*NREF + a) * NW;
    const float* Aj = A + (j*NREF + b) * NW;
    float s = 0.f;
    #pragma unroll
    for (int w = 0; w < NW; ++w) s += Ai[w] * Aj[w] * CW[w];
    ws[OFF_REFC6 + t] = s;
}

// ---- K3: coordination numbers (segment_sum over idx_i) ----------------------
__global__ void k_ncoord(const int* __restrict__ species, const int* __restrict__ eidx,
                         const void* lengths, const void* rcov, const void* en,
                         const void* s6r, float* __restrict__ ws) {
    const bool bf = detect_bf16(s6r);
    int p = blockIdx.x * blockDim.x + threadIdx.x;
    if (p >= NPAIRS) return;
    int i = eidx[p], j = eidx[NPAIRS + p];
    int si = species[i], sj = species[j];
    float r   = ldf(lengths, p, bf) * INV_BOHR;
    float rc  = (4.f/3.f) * (ldf(rcov, si, bf) + ldf(rcov, sj, bf));
    float d   = fabsf(ldf(en, si, bf) - ldf(en, sj, bf)) + CK5;
    float den = CK4 * expf(-(d*d) * INV_K6);
    float cf  = den * 0.5f * (1.f + erff(-CKK * (r - rc) / rc));
    atomicAdd(ws + OFF_NCOORD + i, cf);
}

// ---- K4: per-atom zeta (row-padded to 8; [7]=0) ------------------------------
__global__ void k_zeta(const int* __restrict__ species, const void* pq,
                       const void* zeff, const void* gam,
                       const void* mask, const void* wght, const void* cn,
                       const void* refq, const void* s6r,
                       float* __restrict__ ws) {
    const bool bf = detect_bf16(s6r);
    int k = blockIdx.x * blockDim.x + threadIdx.x;
    if (k >= NATOMS) return;
    int sp = species[k];
    float nce = ws[OFF_NCOORD + k];
    float spq = ws[0];

    float gw[NREF];
    float sum = 0.f;
    #pragma unroll
    for (int a = 0; a < NREF; ++a) {
        float g = 0.f;
        #pragma unroll
        for (int c = 0; c < NC; ++c) {
            int idx = (sp*NREF + a)*NC + c;
            float dlt = nce - ldf(cn, idx, bf);
            g += ldf(mask, idx, bf) * expf(-6.f * ldf(wght, idx, bf) * dlt * dlt);
        }
        gw[a] = g; sum += g;
    }
    // reference: norm = clip(sum,1e-7); where(norm>1e-8, gw/norm, fix) -> always divide
    float inv  = 1.f / fmaxf(sum, 1e-7f);
    float ze   = ldf(zeff, sp, bf);
    float qmod = ze + ldf(pq, k, bf);
    float gm   = ldf(gam, sp, bf);
    #pragma unroll
    for (int a = 0; a < NREF; ++a) {
        float qref = ze + ldf(refq, sp*NREF + a, bf) * spq;
        float zf = (qmod > 1e-8f)
                 ? expf(3.f * (1.f - expf(2.f * gm * (1.f - qref / qmod))))
                 : E3F;
        ws[OFF_ZETA + k*8 + a] = zf * gw[a] * inv;
    }
    ws[OFF_ZETA + k*8 + 7] = 0.f;
}

// ---- K5: pair energies ------------------------------------------------------
__global__ void k_energy(const int* __restrict__ species, const int* __restrict__ eidx,
                         const void* lengths, const void* sqrt_r4r2, const void* s6r,
                         float* __restrict__ ws) {
    const bool bf = detect_bf16(s6r);
    int p = blockIdx.x * blockDim.x + threadIdx.x;
    if (p >= NPAIRS) return;
    int i = eidx[p], j = eidx[NPAIRS + p];
    int si = species[i], sj = species[j];

    const float4* Zi = (const float4*)(ws + OFF_ZETA + (size_t)i * 8);
    const float4* Zj = (const float4*)(ws + OFF_ZETA + (size_t)j * 8);
    float4 zi0 = Zi[0], zi1 = Zi[1];
    float4 zj0 = Zj[0], zj1 = Zj[1];
    float zia[8] = {zi0.x, zi0.y, zi0.z, zi0.w, zi1.x, zi1.y, zi1.z, zi1.w};
    float zja[8] = {zj0.x, zj0.y, zj0.z, zj0.w, zj1.x, zj1.y, zj1.z, zj1.w};

    const float4* R = (const float4*)(ws + OFF_REFC6 + (size_t)(si*ZZ + sj) * RC6PAD);
    float c6 = 0.f;
    #pragma unroll
    for (int k = 0; k < 13; ++k) {
        float4 rv = R[k];
        int e = 4*k;
        // e/7, e%7 are compile-time after full unroll; pads (e>=49) hit zia[7]=0
        c6 += rv.x * zia[(e    )/7] * zja[(e    )%7];
        c6 += rv.y * zia[(e + 1)/7] * zja[(e + 1)%7];
        c6 += rv.z * zia[(e + 2)/7] * zja[(e + 2)%7];
        c6 += rv.w * zia[(e + 3)/7] * zja[(e + 3)%7];
    }

    float r  = ldf(lengths, p, bf) * INV_BOHR;
    float r2 = r * r;
    float r6 = r2 * r2 * r2;
    float r8 = r6 * r2;
    float rr = 3.f * ldf(sqrt_r4r2, si, bf) * ldf(sqrt_r4r2, sj, bf);
    float s6 = ws[1], s8 = ws[2], a1 = ws[3], a2 = ws[4];
    float r0   = a1 * sqrtf(rr) + a2;
    float r0sq = r0 * r0;
    float r0_6 = r0sq * r0sq * r0sq;
    float r0_8 = r0_6 * r0sq;
    float pe = -c6 * (s6 / (r6 + r0_6) + s8 * rr / (r8 + r0_8));
    atomicAdd(ws + OFF_ENERGY + i, pe);
}

// ---- K6: finalize ------------------------------------------------------------
__global__ void k_final(const float* __restrict__ ws, void* out, const void* s6r) {
    const bool bf = detect_bf16(s6r);
    int k = blockIdx.x * blockDim.x + threadIdx.x;
    if (k >= NATOMS) return;
    float v = HALF_HART * ws[OFF_ENERGY + k];
    if (bf) ((__hip_bfloat16*)out)[k] = __float2bfloat16(v);
    else    ((float*)out)[k] = v;
}

// ---- launch ------------------------------------------------------------------
extern "C" void kernel_launch(void* const* d_in, const int* in_sizes, int n_in,
                              void* d_out, int out_size, void* d_ws, size_t ws_size,
                              hipStream_t stream) {
    (void)in_sizes; (void)n_in; (void)out_size; (void)ws_size;

    const int*  species = (const int*)d_in[0];
    const int*  eidx    = (const int*)d_in[1];
    const void* lengths = d_in[2];
    const void* pq      = d_in[3];
    const void* s6r     = d_in[4];
    const void* s8r     = d_in[5];
    const void* a1r     = d_in[6];
    const void* a2r     = d_in[7];
    const void* sqr     = d_in[8];
    const int*  refsys  = (const int*)d_in[9];
    const void* zeff    = d_in[10];
    const void* refh    = d_in[11];
    const void* sscale  = d_in[12];
    const void* secaiw  = d_in[13];
    const void* gam     = d_in[14];
    const void* ascale  = d_in[15];
    const void* alphaiw = d_in[16];
    const void* hcount  = d_in[17];
    const void* cpw     = d_in[18];
    const void* rcov    = d_in[19];
    const void* en      = d_in[20];
    const void* mask    = d_in[21];
    const void* wght    = d_in[22];
    const void* cn      = d_in[23];
    // d_in[24] fixgweights: dead code in the reference (norm clipped >= 1e-7)
    const void* refq    = d_in[25];
    const void* sq4     = d_in[26];

    float* ws = (float*)d_ws;

    // zero the two atomic accumulators (ncoord + energy are contiguous)
    hipMemsetAsync(ws + OFF_NCOORD, 0, (size_t)(2 * NATOMS) * sizeof(float), stream);

    k_prep  <<<(IAW    + 255)/256, 256, 0, stream>>>(refsys, zeff, refh, sscale,
                 secaiw, gam, ascale, alphaiw, hcount, cpw, s6r, s8r, a1r, a2r, sqr, ws);
    k_refc6 <<<(NRC6   + 255)/256, 256, 0, stream>>>(ws);
    k_ncoord<<<(NPAIRS + 255)/256, 256, 0, stream>>>(species, eidx, lengths, rcov, en, s6r, ws);
    k_zeta  <<<(NATOMS + 255)/256, 256, 0, stream>>>(species, pq, zeff, gam, mask, wght, cn, refq, s6r, ws);
    k_energy<<<(NPAIRS + 255)/256, 256, 0, stream>>>(species, eidx, lengths, sq4, s6r, ws);
    k_final <<<(NATOMS + 255)/256, 256, 0, stream>>>(ws, d_out, s6r);
}